// Round 1
// baseline (135.939 us; speedup 1.0000x reference)
//
#include <hip/hip_runtime.h>

#define TL 2048      // sequence length
#define TC 8         // channels
#define TK 84        // kernels
#define TF 4         // biases per kernel
#define TD 4         // dilations
#define KSPLIT 4
#define KPB (TK / KSPLIT)   // 21 kernels per block
#define CL 1024      // l-chunk length processed per half
#define EXT (CL + 64)       // chunk + 32 halo each side

__global__ __launch_bounds__(256, 2) void minirocket_kernel(
    const float* __restrict__ x,        // [B, L, C]
    const float* __restrict__ kernels,  // [K, 9]
    const float* __restrict__ cmask,    // [D, K, C]
    const float* __restrict__ bias,     // [D, K, F]
    const float* __restrict__ fmean,    // [D*K*F]
    const float* __restrict__ fstd,     // [D*K*F]
    float* __restrict__ out)            // [B, D*K*F]
{
    __shared__ float xs[TC][EXT];   // 8*1088*4 = 34816 B
    __shared__ float M[EXT];        // 4352 B
    __shared__ int feats[KPB][TF];  // 336 B

    const int bx  = blockIdx.x;
    const int kh  = bx & (KSPLIT - 1);
    const int d   = (bx >> 2) & 3;
    const int b   = bx >> 4;
    const int tid = threadIdx.x;
    const int lane = tid & 63;
    const int dil = 1 << d;
    const int pad = 4 << d;   // 4*dil
    const int k0  = kh * KPB;

    // zero per-block feature accumulators
    if (tid < KPB * TF) ((int*)feats)[tid] = 0;

    const float4* xv = (const float4*)(x + (size_t)b * TL * TC);

    for (int half = 0; half < 2; ++half) {
        const int lstart = half * CL - 32;

        __syncthreads();  // previous conv reads of M done; safe to restage xs
        // stage x[b, lstart:lstart+EXT, :] transposed into xs (OOB -> 0)
        for (int e = tid; e < EXT; e += 256) {
            const int l = lstart + e;
            float4 a = make_float4(0.f, 0.f, 0.f, 0.f);
            float4 c4 = make_float4(0.f, 0.f, 0.f, 0.f);
            if (l >= 0 && l < TL) {
                a  = xv[2 * l];
                c4 = xv[2 * l + 1];
            }
            xs[0][e] = a.x;  xs[1][e] = a.y;  xs[2][e] = a.z;  xs[3][e] = a.w;
            xs[4][e] = c4.x; xs[5][e] = c4.y; xs[6][e] = c4.z; xs[7][e] = c4.w;
        }
        __syncthreads();

        for (int kk = 0; kk < KPB; ++kk) {
            const int k = k0 + kk;

            // uniform per-kernel parameters (scalar loads)
            unsigned bits = 0;
            const float* cm = cmask + ((size_t)d * TK + k) * TC;
            #pragma unroll
            for (int c = 0; c < TC; ++c)
                bits |= (cm[c] != 0.f) ? (1u << c) : 0u;

            float w[9];
            #pragma unroll
            for (int j = 0; j < 9; ++j) w[j] = kernels[k * 9 + j];

            const float* bp = bias + ((size_t)d * TK + k) * TF;
            const float b0 = bp[0], b1 = bp[1], b2 = bp[2], b3 = bp[3];
            const bool parityOdd = ((d + k) & 1) != 0;

            // ---- mixed phase: masked channel sum over ext range ----
            for (int e = tid; e < EXT; e += 256) {
                float m = 0.f;
                #pragma unroll
                for (int c = 0; c < TC; ++c)
                    if (bits & (1u << c)) m += xs[c][e];
                M[e] = m;
            }
            __syncthreads();

            // ---- conv + PPV count ----
            int c0 = 0, c1 = 0, c2 = 0, c3 = 0;
            for (int i = tid; i < CL; i += 256) {
                const int l = half * CL + i;          // global position
                const float* mp = &M[i + 32];
                float r = 0.f;
                #pragma unroll
                for (int j = 0; j < 9; ++j)
                    r += w[j] * mp[(j - 4) * dil];
                const bool inc = !parityOdd || (l >= pad && l < TL - pad);
                c0 += __popcll(__ballot(inc && (r > b0)));
                c1 += __popcll(__ballot(inc && (r > b1)));
                c2 += __popcll(__ballot(inc && (r > b2)));
                c3 += __popcll(__ballot(inc && (r > b3)));
            }
            if (lane == 0) {
                atomicAdd(&feats[kk][0], c0);
                atomicAdd(&feats[kk][1], c1);
                atomicAdd(&feats[kk][2], c2);
                atomicAdd(&feats[kk][3], c3);
            }
            __syncthreads();  // M reads done before next kk overwrites
        }
    }

    // ---- epilogue: normalize and write ----
    if (tid < KPB * TF) {
        const int kk = tid >> 2, f = tid & 3;
        const int k = k0 + kk;
        const bool parityOdd = ((d + k) & 1) != 0;
        const float denom = parityOdd ? (float)(TL - 2 * pad) : (float)TL;
        const float val = (float)feats[kk][f] / denom;
        const int fidx = d * (TK * TF) + k * TF + f;
        out[(size_t)b * (TD * TK * TF) + fidx] = (val - fmean[fidx]) / fstd[fidx];
    }
}

extern "C" void kernel_launch(void* const* d_in, const int* in_sizes, int n_in,
                              void* d_out, int out_size, void* d_ws, size_t ws_size,
                              hipStream_t stream) {
    const float* x       = (const float*)d_in[0];
    const float* kern    = (const float*)d_in[1];
    const float* cmask   = (const float*)d_in[2];
    const float* bias    = (const float*)d_in[3];
    const float* fmean   = (const float*)d_in[4];
    const float* fstd    = (const float*)d_in[5];
    float* out           = (float*)d_out;

    dim3 grid(64 * TD * KSPLIT);  // 1024 blocks: (b, d, k-quarter)
    dim3 block(256);
    hipLaunchKernelGGL(minirocket_kernel, grid, block, 0, stream,
                       x, kern, cmask, bias, fmean, fstd, out);
}

// Round 3
// 95.444 us; speedup vs baseline: 1.4243x; 1.4243x over previous
//
#include <hip/hip_runtime.h>

#define TL 2048
#define TC 8
#define TK 84
#define TF 4
#define TD 4
#define TEXT 320              // tile: 256 outputs + 32 halo each side
#define SROW 352              // padded phase-major row length (floats)
#define NFEAT (TD * TK * TF)  // 1344

// Phase-major index: ext position e -> (e & (DIL-1)) * PS + (e >> log2(DIL)).
// PS multiple of 4 so 12-float conv windows are float4-aligned.
template <int DIL>
__device__ __forceinline__ void block_work(
    float (*__restrict__ Stab)[SROW],
    int (*__restrict__ feats)[TF],
    const int* __restrict__ kbits,
    const float4* __restrict__ biasL4,
    const float4 (*__restrict__ kwL4)[3],
    const float* __restrict__ xb,
    int tid, int lane, int w, int P0)
{
    constexpr int LD = (DIL == 8) ? 3 : (DIL == 4) ? 2 : (DIL == 2) ? 1 : 0;
    constexpr int PS = (DIL == 1) ? 320 : (DIL == 2) ? 168 : (DIL == 4) ? 84 : 44;
    const int E0 = P0 - 32;

    // ---- build phase-major subset-sum tables (only cross-lane producer) ----
    for (int e = tid; e < TEXT; e += 256) {
        const int pos = E0 + e;
        float ch[8] = {0.f, 0.f, 0.f, 0.f, 0.f, 0.f, 0.f, 0.f};
        if (pos >= 0 && pos < TL) {
            const float4* xp = (const float4*)(xb + (size_t)pos * TC);
            const float4 a = xp[0], h = xp[1];
            ch[0] = a.x; ch[1] = a.y; ch[2] = a.z; ch[3] = a.w;
            ch[4] = h.x; ch[5] = h.y; ch[6] = h.z; ch[7] = h.w;
        }
        float lo[16], hi[16];
        lo[0] = 0.f; hi[0] = 0.f;
        #pragma unroll
        for (int m = 1; m < 16; ++m) lo[m] = lo[m & (m - 1)] + ch[__builtin_ctz(m)];
        #pragma unroll
        for (int m = 1; m < 16; ++m) hi[m] = hi[m & (m - 1)] + ch[4 + __builtin_ctz(m)];
        const int pe = (e & (DIL - 1)) * PS + (e >> LD);
        #pragma unroll
        for (int s = 0; s < 16; ++s) { Stab[s][pe] = lo[s]; Stab[16 + s][pe] = hi[s]; }
    }
    __syncthreads();

    // ---- per-wave kernel loop: wave w owns k = 4g + w ----
    const int p  = lane & (DIL - 1);
    const int jr = lane >> LD;
    const int f4b = p * (PS / 4) + (8 >> LD) - 1 + jr;

    for (int g = 0; g < 21; ++g) {
        const int k = g * 4 + w;
        const int bits = kbits[k];
        const float4* slo = (const float4*)&Stab[bits & 15][0];
        const float4* shi = (const float4*)&Stab[16 + (bits >> 4)][0];
        const float4 a0 = slo[f4b], a1 = slo[f4b + 1], a2 = slo[f4b + 2];
        const float4 h0 = shi[f4b], h1 = shi[f4b + 1], h2 = shi[f4b + 2];
        float l[12];
        l[0] = a0.x + h0.x; l[1] = a0.y + h0.y; l[2]  = a0.z + h0.z; l[3]  = a0.w + h0.w;
        l[4] = a1.x + h1.x; l[5] = a1.y + h1.y; l[6]  = a1.z + h1.z; l[7]  = a1.w + h1.w;
        l[8] = a2.x + h2.x; l[9] = a2.y + h2.y; l[10] = a2.z + h2.z; l[11] = a2.w + h2.w;

        const float4 bq = biasL4[k];
        const float4 w0 = kwL4[k][0], w1 = kwL4[k][1], w2 = kwL4[k][2];
        const float wv[9] = {w0.x, w0.y, w0.z, w0.w, w1.x, w1.y, w1.z, w1.w, w2.x};
        const bool odd = ((LD + k) & 1) != 0;

        int c0 = 0, c1 = 0, c2 = 0, c3 = 0;
        #pragma unroll
        for (int i = 0; i < 4; ++i) {
            float r = 0.f;
            #pragma unroll
            for (int j = 0; j < 9; ++j) r = fmaf(wv[j], l[i + j], r);
            const int apos = P0 + p + (4 * jr + i) * DIL;
            const bool ok = (!odd) || (apos >= 4 * DIL && apos < TL - 4 * DIL);
            const unsigned long long mok = __ballot(ok);
            c0 += __popcll(__ballot(r > bq.x) & mok);
            c1 += __popcll(__ballot(r > bq.y) & mok);
            c2 += __popcll(__ballot(r > bq.z) & mok);
            c3 += __popcll(__ballot(r > bq.w) & mok);
        }
        if (lane == 0) {
            feats[k][0] += c0; feats[k][1] += c1;
            feats[k][2] += c2; feats[k][3] += c3;
        }
    }
}

__global__ __launch_bounds__(256, 3) void mr_main(
    const float* __restrict__ x,      // [B, L, C]
    const float* __restrict__ kern,   // [K, 9]
    const float* __restrict__ cmask,  // [D, K, C]
    const float* __restrict__ bias,   // [D, K, F]
    const float* __restrict__ fstd,   // [NFEAT]
    float* __restrict__ out)          // [B, NFEAT], pre-init to -mean/std
{
    __shared__ __align__(16) float Stab[32][SROW];   // 45056 B
    __shared__ int   feats[TK][TF];
    __shared__ int   kbits[TK];
    __shared__ __align__(16) float4 biasL4[TK];
    __shared__ __align__(16) float4 kwL4[TK][3];

    const int bx = blockIdx.x;
    const int q = bx & 3, d_idx = (bx >> 2) & 3, b = bx >> 4;
    const int tid = threadIdx.x, lane = tid & 63, w = tid >> 6;
    const float* xb = x + (size_t)b * TL * TC;

    for (int kk = tid; kk < TK; kk += 256) {
        const float* cm = cmask + ((size_t)d_idx * TK + kk) * TC;
        int bits = 0;
        #pragma unroll
        for (int c = 0; c < TC; ++c) bits |= (cm[c] != 0.f) ? (1 << c) : 0;
        kbits[kk] = bits;
        const float* bp = bias + ((size_t)d_idx * TK + kk) * TF;
        biasL4[kk] = make_float4(bp[0], bp[1], bp[2], bp[3]);
        const float* kp = kern + kk * 9;
        kwL4[kk][0] = make_float4(kp[0], kp[1], kp[2], kp[3]);
        kwL4[kk][1] = make_float4(kp[4], kp[5], kp[6], kp[7]);
        kwL4[kk][2] = make_float4(kp[8], 0.f, 0.f, 0.f);
    }
    for (int i2 = tid; i2 < TK * TF; i2 += 256) ((int*)feats)[i2] = 0;
    // visibility of consts/feats: covered by the build->consume sync inside block_work

    for (int t2 = 0; t2 < 2; ++t2) {
        if (t2) __syncthreads();   // prior tile's Stab readers done before rebuild
        const int P0 = q * 512 + t2 * 256;
        switch (d_idx) {
            case 0:  block_work<1>(Stab, feats, kbits, biasL4, kwL4, xb, tid, lane, w, P0); break;
            case 1:  block_work<2>(Stab, feats, kbits, biasL4, kwL4, xb, tid, lane, w, P0); break;
            case 2:  block_work<4>(Stab, feats, kbits, biasL4, kwL4, xb, tid, lane, w, P0); break;
            default: block_work<8>(Stab, feats, kbits, biasL4, kwL4, xb, tid, lane, w, P0); break;
        }
    }

    __syncthreads();
    for (int idx = tid; idx < TK * TF; idx += 256) {
        const int k = idx >> 2;
        const bool odd2 = ((d_idx + k) & 1) != 0;
        const float denom = odd2 ? (float)(TL - (8 << d_idx)) : (float)TL;
        const int fid = d_idx * (TK * TF) + idx;
        const float scale = 1.0f / (denom * fstd[fid]);
        atomicAdd(&out[(size_t)b * NFEAT + fid], (float)feats[k][idx & 3] * scale);
    }
}

__global__ void mr_init(const float* __restrict__ fmean, const float* __restrict__ fstd,
                        float* __restrict__ out) {
    const int o = blockIdx.x * 256 + threadIdx.x;
    if (o < 64 * NFEAT) {
        const int fid = o % NFEAT;
        out[o] = -fmean[fid] / fstd[fid];
    }
}

extern "C" void kernel_launch(void* const* d_in, const int* in_sizes, int n_in,
                              void* d_out, int out_size, void* d_ws, size_t ws_size,
                              hipStream_t stream) {
    const float* x     = (const float*)d_in[0];
    const float* kern  = (const float*)d_in[1];
    const float* cmask = (const float*)d_in[2];
    const float* bias  = (const float*)d_in[3];
    const float* fmean = (const float*)d_in[4];
    const float* fstd  = (const float*)d_in[5];
    float* out = (float*)d_out;

    hipLaunchKernelGGL(mr_init, dim3((64 * NFEAT + 255) / 256), dim3(256), 0, stream,
                       fmean, fstd, out);
    hipLaunchKernelGGL(mr_main, dim3(64 * TD * 4), dim3(256), 0, stream,
                       x, kern, cmask, bias, fstd, out);
}